// Round 1
// baseline (334.909 us; speedup 1.0000x reference)
//
#include <hip/hip_runtime.h>
#include <hip/hip_bf16.h>

// Problem constants
#define BB 32
#define SS 1024
#define TT 64
#define HD 1024   // 2H
#define FF 2048   // 4H
#define MM (BB*SS) // 32768

typedef __attribute__((ext_vector_type(4))) float f32x4;
typedef __attribute__((ext_vector_type(8))) short bf16x8;

__device__ __forceinline__ unsigned short f2bf(float f) {
  __hip_bfloat16 h = __float2bfloat16(f);
  return __builtin_bit_cast(unsigned short, h);
}

__device__ __forceinline__ void gll16(const void* g, void* l) {
  __builtin_amdgcn_global_load_lds(
      (const __attribute__((address_space(1))) void*)g,
      (__attribute__((address_space(3))) void*)l, 16, 0, 0);
}

// ---------------------------------------------------------------- converts
__global__ void cvt_bf16_kernel(const float* __restrict__ x,
                                unsigned short* __restrict__ y, int n4) {
  int stride = gridDim.x * blockDim.x;
  for (int i = blockIdx.x * blockDim.x + threadIdx.x; i < n4; i += stride) {
    float4 v = reinterpret_cast<const float4*>(x)[i];
    ushort4 o;
    o.x = f2bf(v.x); o.y = f2bf(v.y); o.z = f2bf(v.z); o.w = f2bf(v.w);
    reinterpret_cast<ushort4*>(y)[i] = o;
  }
}

// transpose+convert: in fp32 [bz][R][C] -> out bf16 [bz][C][R]
__global__ void tcvt_kernel(const float* __restrict__ in,
                            unsigned short* __restrict__ out, int R, int C) {
  __shared__ float tile[32][33];
  const int bz = blockIdx.z;
  const float* ip = in + (size_t)bz * R * C;
  unsigned short* op = out + (size_t)bz * R * C;
  const int c0 = blockIdx.x * 32, r0 = blockIdx.y * 32;
  const int tx = threadIdx.x, ty = threadIdx.y; // (32, 8)
#pragma unroll
  for (int j = 0; j < 4; ++j)
    tile[ty + j * 8][tx] = ip[(size_t)(r0 + ty + j * 8) * C + c0 + tx];
  __syncthreads();
#pragma unroll
  for (int j = 0; j < 4; ++j)
    op[(size_t)(c0 + ty + j * 8) * R + r0 + tx] = f2bf(tile[tx][ty + j * 8]);
}

// ---------------------------------------------------------------- attention
// grid (S/64, B), block 256 (4 waves). Each block: 64 hidden rows vs all T=64.
__global__ __launch_bounds__(256) void attn_kernel(
    const unsigned short* __restrict__ hid_bf,   // [B][S][D]
    const unsigned short* __restrict__ tgt_bf,   // [B][T][D]
    const unsigned short* __restrict__ tgtT_bf,  // [B][D][T]
    unsigned short* __restrict__ ti_bf)          // [B][S][D]
{
  __shared__ unsigned short Qs[64 * 32];
  __shared__ unsigned short Ks[64 * 32];
  __shared__ unsigned short Ps[64 * 72];  // pad 64->72: byte stride 144 (16B aligned, 2-way only)

  const int tid = threadIdx.x;
  const int w = tid >> 6, l = tid & 63;
  const int lrow = l & 15, lk = l >> 4;
  const int b = blockIdx.y;
  const int sbase = blockIdx.x * 64;

  const size_t hbase = ((size_t)b * SS + sbase) * HD;
  const size_t tbase = (size_t)b * TT * HD;
  const int srow = tid >> 2;        // 0..63
  const int scol = (tid & 3) * 8;   // 0,8,16,24

  f32x4 accs[4] = {};
  for (int kt = 0; kt < 32; ++kt) {
    const int kk = kt * 32;
    gll16(hid_bf + hbase + (size_t)srow * HD + kk + scol, Qs + w * 512);
    gll16(tgt_bf + tbase + (size_t)srow * HD + kk + scol, Ks + w * 512);
    __syncthreads();
    bf16x8 a = *reinterpret_cast<const bf16x8*>(&Qs[(w * 16 + lrow) * 32 + lk * 8]);
#pragma unroll
    for (int ct = 0; ct < 4; ++ct) {
      bf16x8 bb = *reinterpret_cast<const bf16x8*>(&Ks[(ct * 16 + lrow) * 32 + lk * 8]);
      accs[ct] = __builtin_amdgcn_mfma_f32_16x16x32_bf16(a, bb, accs[ct], 0, 0, 0);
    }
    __syncthreads();
  }

  // softmax over t (64 cols). lane holds rows lk*4+j (rel), cols ct*16+lrow.
  float p[4][4];
#pragma unroll
  for (int j = 0; j < 4; ++j) {
    float mx = fmaxf(fmaxf(accs[0][j], accs[1][j]), fmaxf(accs[2][j], accs[3][j]));
#pragma unroll
    for (int d = 1; d < 16; d <<= 1) mx = fmaxf(mx, __shfl_xor(mx, d, 64));
    float sum = 0.f;
#pragma unroll
    for (int ct = 0; ct < 4; ++ct) { p[ct][j] = __expf(accs[ct][j] - mx); sum += p[ct][j]; }
#pragma unroll
    for (int d = 1; d < 16; d <<= 1) sum += __shfl_xor(sum, d, 64);
    float inv = 1.f / sum;
#pragma unroll
    for (int ct = 0; ct < 4; ++ct) p[ct][j] *= inv;
  }
#pragma unroll
  for (int j = 0; j < 4; ++j)
#pragma unroll
    for (int ct = 0; ct < 4; ++ct)
      Ps[(w * 16 + lk * 4 + j) * 72 + ct * 16 + lrow] = f2bf(p[ct][j]);
  __syncthreads();

  // PV: ti(64x1024) = P(64x64) @ target(64x1024); B-frags from tgtT [D][T]
  const size_t tTbase = (size_t)b * HD * TT;
  for (int chunk = 0; chunk < 16; ++chunk) {
    const int colbase = chunk * 64;
    f32x4 acco[4] = {};
#pragma unroll
    for (int kk2 = 0; kk2 < 2; ++kk2) {
      bf16x8 a = *reinterpret_cast<const bf16x8*>(&Ps[(w * 16 + lrow) * 72 + kk2 * 32 + lk * 8]);
#pragma unroll
      for (int ct = 0; ct < 4; ++ct) {
        const unsigned short* gp =
            tgtT_bf + tTbase + (size_t)(colbase + ct * 16 + lrow) * TT + kk2 * 32 + lk * 8;
        bf16x8 bb = *reinterpret_cast<const bf16x8*>(gp);
        acco[ct] = __builtin_amdgcn_mfma_f32_16x16x32_bf16(a, bb, acco[ct], 0, 0, 0);
      }
    }
#pragma unroll
    for (int ct = 0; ct < 4; ++ct)
#pragma unroll
      for (int j = 0; j < 4; ++j)
        ti_bf[hbase + (size_t)(w * 16 + lk * 4 + j) * HD + colbase + ct * 16 + lrow] =
            f2bf(acco[ct][j]);
  }
}

// ---------------------------------------------------------------- transform GEMM
// out = tanh([hidden|ti] @ W + b) + hidden_f32.  M=32768, K=2048, N=1024.
// 128x128 tile, BK=32, 4 waves, 4x4 acc/wave (m97 structure).
__global__ __launch_bounds__(256) void gemm_kernel(
    const unsigned short* __restrict__ hid_bf,  // [M][1024]
    const unsigned short* __restrict__ ti_bf,   // [M][1024]
    const unsigned short* __restrict__ Wt_bf,   // [1024][2048]  (n-major)
    const float* __restrict__ bias,             // [1024]
    const float* __restrict__ hid_f32,          // [M][1024]
    float* __restrict__ out)                    // [M][1024]
{
  __shared__ unsigned short As[128 * 32];
  __shared__ unsigned short Bs[128 * 32];
  const int tid = threadIdx.x;
  const int w = tid >> 6, l = tid & 63;
  const int wr = w >> 1, wc = w & 1;
  const int lrow = l & 15, lk = l >> 4;
  const int nbase = blockIdx.x * 128;
  const int mbase = blockIdx.y * 128;
  const int srow = tid >> 2;
  const int scol = (tid & 3) * 8;

  f32x4 acc[4][4] = {};

  for (int kt = 0; kt < 64; ++kt) {
    const int kk = kt * 32;
    const unsigned short* Ap = (kk < 1024) ? (hid_bf + kk) : (ti_bf + (kk - 1024));
    gll16(Ap + (size_t)(mbase + srow) * HD + scol, As + w * 512);
    gll16(Ap + (size_t)(mbase + 64 + srow) * HD + scol, As + 2048 + w * 512);
    gll16(Wt_bf + (size_t)(nbase + srow) * FF + kk + scol, Bs + w * 512);
    gll16(Wt_bf + (size_t)(nbase + 64 + srow) * FF + kk + scol, Bs + 2048 + w * 512);
    __syncthreads();
    bf16x8 af[4], bfr[4];
#pragma unroll
    for (int m = 0; m < 4; ++m)
      af[m] = *reinterpret_cast<const bf16x8*>(&As[(wr * 64 + m * 16 + lrow) * 32 + lk * 8]);
#pragma unroll
    for (int n = 0; n < 4; ++n)
      bfr[n] = *reinterpret_cast<const bf16x8*>(&Bs[(wc * 64 + n * 16 + lrow) * 32 + lk * 8]);
#pragma unroll
    for (int m = 0; m < 4; ++m)
#pragma unroll
      for (int n = 0; n < 4; ++n)
        acc[m][n] = __builtin_amdgcn_mfma_f32_16x16x32_bf16(af[m], bfr[n], acc[m][n], 0, 0, 0);
    __syncthreads();
  }

#pragma unroll
  for (int m = 0; m < 4; ++m) {
    const int row = mbase + wr * 64 + m * 16 + lk * 4;
#pragma unroll
    for (int n = 0; n < 4; ++n) {
      const int col = nbase + wc * 64 + n * 16 + lrow;
      const float bv = bias[col];
#pragma unroll
      for (int j = 0; j < 4; ++j) {
        float x = acc[m][n][j] + bv;
        float xc = fminf(fmaxf(x, -15.f), 15.f);
        float e2 = __expf(2.f * xc);
        float th = (e2 - 1.f) / (e2 + 1.f);
        size_t oi = (size_t)(row + j) * HD + col;
        out[oi] = th + hid_f32[oi];
      }
    }
  }
}

// ---------------------------------------------------------------- launch
extern "C" void kernel_launch(void* const* d_in, const int* in_sizes, int n_in,
                              void* d_out, int out_size, void* d_ws, size_t ws_size,
                              hipStream_t stream) {
  const float* tgt  = (const float*)d_in[0];  // (B,T,2H)
  const float* hid  = (const float*)d_in[1];  // (B,S,2H)
  const float* W    = (const float*)d_in[2];  // (4H,2H)
  const float* bias = (const float*)d_in[3];  // (2H,)
  float* out = (float*)d_out;

  char* ws = (char*)d_ws;
  unsigned short* hid_bf  = (unsigned short*)(ws);                    //  64 MiB
  unsigned short* ti_bf   = (unsigned short*)(ws + 67108864);         //  64 MiB
  unsigned short* tgt_bf  = (unsigned short*)(ws + 134217728);        //   4 MiB
  unsigned short* tgtT_bf = (unsigned short*)(ws + 138412032);        //   4 MiB
  unsigned short* Wt_bf   = (unsigned short*)(ws + 142606336);        //   4 MiB

  cvt_bf16_kernel<<<2048, 256, 0, stream>>>(hid, hid_bf, (BB * SS * HD) / 4);
  cvt_bf16_kernel<<<512, 256, 0, stream>>>(tgt, tgt_bf, (BB * TT * HD) / 4);
  tcvt_kernel<<<dim3(HD / 32, TT / 32, BB), dim3(32, 8), 0, stream>>>(tgt, tgtT_bf, TT, HD);
  tcvt_kernel<<<dim3(HD / 32, FF / 32, 1), dim3(32, 8), 0, stream>>>(W, Wt_bf, FF, HD);
  attn_kernel<<<dim3(SS / 64, BB), 256, 0, stream>>>(hid_bf, tgt_bf, tgtT_bf, ti_bf);
  gemm_kernel<<<dim3(HD / 128, MM / 128), 256, 0, stream>>>(hid_bf, ti_bf, Wt_bf, bias, hid, out);
}